// Round 11
// baseline (99.926 us; speedup 1.0000x reference)
//
#include <hip/hip_runtime.h>
#include <hip/hip_bf16.h>

// Tucker: out[a,s,t] = sum_{f,e,g} act[a,f]*state[s,e]*core[f,e,g]*state[t,g]
// A=64, S=T=1024, E=G=64, F=32.
//
// R10 (occupancy-cap theory): R9 confirmed store ISSUE RATE is the limiter
// (66.2us at ~24 waves/CU). Shrink per-wave state to fit 64 VGPR ->
// launch_bounds(256,8) = 32 waves/CU: 4096 blocks x 16 rows, single B-frag
// pair, 1 store/iter. Store pattern unchanged (proven irrelevant R0-R8).
//  prep: state->bf16 (sb) + Wt[a][g][e]=sum_f act*core (bf16)  [unchanged]
//  gemm: per block: 16x64 U tile (1 MFMA pair/wave) -> LDS relayout -> sweep

typedef __attribute__((ext_vector_type(8))) __bf16 bf16x8;
typedef __attribute__((ext_vector_type(4))) float f32x4;

static __device__ __forceinline__ unsigned short f2bf(float x) {
    union { float f; unsigned int u; } c; c.f = x;
    unsigned int lsb = (c.u >> 16) & 1u;
    c.u += 0x7fffu + lsb;               // round-to-nearest-even
    return (unsigned short)(c.u >> 16);
}

// ---- prep: fused state->bf16 conversion + Wt build (unchanged) ----
__global__ __launch_bounds__(256) void prep(const float* __restrict__ state,
                                            const float* __restrict__ act,
                                            const float* __restrict__ core,
                                            unsigned short* __restrict__ sb,
                                            unsigned short* __restrict__ wt) {
    int bx = blockIdx.x;          // 256 blocks: a(64) x chunk(4)
    int a = bx >> 2, ch = bx & 3;
    int t = threadIdx.x;
    {   // state cvt: 16384 float4s, 64 per block (threads 0..63)
        if (t < 64) {
            int i = bx * 64 + t;
            float4 v = reinterpret_cast<const float4*>(state)[i];
            union { unsigned short u[4]; unsigned long long ull; } r;
            r.u[0] = f2bf(v.x); r.u[1] = f2bf(v.y); r.u[2] = f2bf(v.z); r.u[3] = f2bf(v.w);
            reinterpret_cast<unsigned long long*>(sb)[i] = r.ull;
        }
    }
    __shared__ float af[32];
    if (t < 32) af[t] = act[a * 32 + t];
    __syncthreads();
#pragma unroll
    for (int i = 0; i < 4; ++i) {
        int idx = ch * 1024 + i * 256 + t;   // 1024 (e,g) pairs per block
        int e = idx >> 6, g = idx & 63;
        float acc = 0.f;
#pragma unroll
        for (int f = 0; f < 32; ++f)
            acc += af[f] * core[(f * 64 + e) * 64 + g];
        wt[a * 4096 + g * 64 + e] = f2bf(acc);   // store transposed (g,e)
    }
}

// ---- gemm: 4096 blocks x 16 rows; minimal-VGPR pipelined t-quarter sweep ----
__global__ __launch_bounds__(256, 8) void gemm(const unsigned short* __restrict__ sb,
                                               const unsigned short* __restrict__ wt,
                                               float* __restrict__ out) {
    __shared__ unsigned short uls[16 * 72];   // U tile, pitch 72 bf16 (2304 B)

    int bx = blockIdx.x;                  // 4096 blocks
    int rb = (bx & 7) * 512 + (bx >> 3);  // XCD-chunked, bijective (4096 = 8*512)
    int wid = threadIdx.x >> 6, lane = threadIdx.x & 63;
    int lr = lane & 15, lk = (lane >> 4) * 8;
    int rr = (lane >> 4) * 4;
    size_t R0 = (size_t)rb * 16;          // first out row (flat (a,s))
    int a = rb >> 6;                      // 64 blocks per a
    int sloc = (rb & 63) * 16;            // s-within-a of first row

    // ---- preamble: U[s][g] = sum_e sb[sloc+s][e]*wta[g][e], s in [0,16), g in [0,64)
    // wave w computes g-quarter w (16 g) for all 16 s.
    {
        const unsigned short* wta = wt + a * 4096;
        bf16x8 ag0 = *reinterpret_cast<const bf16x8*>(wta + (wid * 16 + lr) * 64 + lk);
        bf16x8 ag1 = *reinterpret_cast<const bf16x8*>(wta + (wid * 16 + lr) * 64 + 32 + lk);
        bf16x8 bs0 = *reinterpret_cast<const bf16x8*>(sb + (sloc + lr) * 64 + lk);
        bf16x8 bs1 = *reinterpret_cast<const bf16x8*>(sb + (sloc + lr) * 64 + 32 + lk);
        f32x4 uacc = {};
        uacc = __builtin_amdgcn_mfma_f32_16x16x32_bf16(ag0, bs0, uacc, 0, 0, 0);
        uacc = __builtin_amdgcn_mfma_f32_16x16x32_bf16(ag1, bs1, uacc, 0, 0, 0);
        // lane holds U[s = lr][g = wid*16 + rr + q], q=0..3 -> pack 8B to LDS
        union { unsigned short h[4]; unsigned long long ull; } pk;
#pragma unroll
        for (int q = 0; q < 4; ++q) pk.h[q] = f2bf(uacc[q]);
        *reinterpret_cast<unsigned long long*>(uls + lr * 72 + wid * 16 + rr) = pk.ull;
    }
    __syncthreads();

    // B-frags: U rows (out-local row = lr), read once from LDS
    bf16x8 b0 = *reinterpret_cast<const bf16x8*>(uls + lr * 72 + lk);
    bf16x8 b1 = *reinterpret_cast<const bf16x8*>(uls + lr * 72 + 32 + lk);

    // ---- t-sweep: wave w covers t in [w*256, w*256+256) for all 16 rows ----
    int t0w = wid * 256;
    const unsigned short* sbw = sb + (t0w + lr) * 64;
    float* ob = out + (R0 + lr) * 1024 + t0w + rr;

#pragma unroll 8
    for (int mm = 0; mm < 16; ++mm) {
        bf16x8 a0 = *reinterpret_cast<const bf16x8*>(sbw + mm * 16 * 64 + lk);
        bf16x8 a1 = *reinterpret_cast<const bf16x8*>(sbw + mm * 16 * 64 + 32 + lk);
        f32x4 acc = {};
        acc = __builtin_amdgcn_mfma_f32_16x16x32_bf16(a0, b0, acc, 0, 0, 0);
        acc = __builtin_amdgcn_mfma_f32_16x16x32_bf16(a1, b1, acc, 0, 0, 0);
        // lane: out[R0 + lr][t0w + mm*16 + rr + q] -> one 16B store
        *reinterpret_cast<f32x4*>(ob + mm * 16) = acc;
    }
}

extern "C" void kernel_launch(void* const* d_in, const int* in_sizes, int n_in,
                              void* d_out, int out_size, void* d_ws, size_t ws_size,
                              hipStream_t stream) {
    const float* state = (const float*)d_in[0];   // 1024 x 64
    const float* act   = (const float*)d_in[1];   // 64 x 32
    const float* core  = (const float*)d_in[2];   // 32 x 64 x 64
    float* out = (float*)d_out;                   // 64 x 1024 x 1024

    unsigned short* sb = (unsigned short*)d_ws;   // state bf16: 65536 (128 KB)
    unsigned short* wt = sb + 65536;              // Wt bf16:   262144 (512 KB)

    prep<<<256, 256, 0, stream>>>(state, act, core, sb, wt);
    gemm<<<4096, 256, 0, stream>>>(sb, wt, out);
}

// Round 12
// 65.785 us; speedup vs baseline: 1.5190x; 1.5190x over previous
//
#include <hip/hip_runtime.h>
#include <hip/hip_bf16.h>

// Tucker: out[a,s,t] = sum_{f,e,g} act[a,f]*state[s,e]*core[f,e,g]*state[t,g]
// A=64, S=T=1024, E=G=64, F=32.
//
// R11 (depth x occupancy product): R9=66.2us @ (256,6)~6-deep x 24 waves/CU.
// R10 (64-VGPR cap) crushed depth -> 99.9us: depth > wave count. This round:
// (256,4) = 128-VGPR cap, 16 waves/CU, FULL unroll-16 sweep -> ~2x pipeline
// depth, x0.67 waves = net +35% outstanding stores/CU. Everything else is
// byte-identical to R9 (2048 blocks x 32 rows, dual chain, proven stores).
//  prep: state->bf16 (sb) + Wt[a][g][e]=sum_f act*core (bf16)  [unchanged]

typedef __attribute__((ext_vector_type(8))) __bf16 bf16x8;
typedef __attribute__((ext_vector_type(4))) float f32x4;

static __device__ __forceinline__ unsigned short f2bf(float x) {
    union { float f; unsigned int u; } c; c.f = x;
    unsigned int lsb = (c.u >> 16) & 1u;
    c.u += 0x7fffu + lsb;               // round-to-nearest-even
    return (unsigned short)(c.u >> 16);
}

// ---- prep: fused state->bf16 conversion + Wt build (unchanged) ----
__global__ __launch_bounds__(256) void prep(const float* __restrict__ state,
                                            const float* __restrict__ act,
                                            const float* __restrict__ core,
                                            unsigned short* __restrict__ sb,
                                            unsigned short* __restrict__ wt) {
    int bx = blockIdx.x;          // 256 blocks: a(64) x chunk(4)
    int a = bx >> 2, ch = bx & 3;
    int t = threadIdx.x;
    {   // state cvt: 16384 float4s, 64 per block (threads 0..63)
        if (t < 64) {
            int i = bx * 64 + t;
            float4 v = reinterpret_cast<const float4*>(state)[i];
            union { unsigned short u[4]; unsigned long long ull; } r;
            r.u[0] = f2bf(v.x); r.u[1] = f2bf(v.y); r.u[2] = f2bf(v.z); r.u[3] = f2bf(v.w);
            reinterpret_cast<unsigned long long*>(sb)[i] = r.ull;
        }
    }
    __shared__ float af[32];
    if (t < 32) af[t] = act[a * 32 + t];
    __syncthreads();
#pragma unroll
    for (int i = 0; i < 4; ++i) {
        int idx = ch * 1024 + i * 256 + t;   // 1024 (e,g) pairs per block
        int e = idx >> 6, g = idx & 63;
        float acc = 0.f;
#pragma unroll
        for (int f = 0; f < 32; ++f)
            acc += af[f] * core[(f * 64 + e) * 64 + g];
        wt[a * 4096 + g * 64 + e] = f2bf(acc);   // store transposed (g,e)
    }
}

// ---- gemm: 2048 blocks x 32 rows; deep-pipelined t-quarter sweep ----
__global__ __launch_bounds__(256, 4) void gemm(const unsigned short* __restrict__ sb,
                                               const unsigned short* __restrict__ wt,
                                               float* __restrict__ out) {
    __shared__ unsigned short uls[32 * 72];   // U tile, pitch 72 bf16 (4608 B)

    int bx = blockIdx.x;                  // 2048 blocks
    int rb = (bx & 7) * 256 + (bx >> 3);  // XCD-chunked, bijective (2048 = 8*256)
    int wid = threadIdx.x >> 6, lane = threadIdx.x & 63;
    int lr = lane & 15, lk = (lane >> 4) * 8;
    int rr = (lane >> 4) * 4;
    size_t R0 = (size_t)rb * 32;          // first out row (flat (a,s))
    int a = rb >> 5;                      // 32 blocks per a
    int sloc = (rb & 31) * 32;            // s-within-a of first row

    // ---- preamble: U[s][g] = sum_e sb[sloc+s][e]*wta[g][e], s in [0,32), g in [0,64)
    // wave w: s-half sh=w&1 (16 rows), g-half gh=w>>1 (32 g)
    {
        const unsigned short* wta = wt + a * 4096;
        int sh = wid & 1, gh = wid >> 1;
        bf16x8 bs0 = *reinterpret_cast<const bf16x8*>(sb + (sloc + sh * 16 + lr) * 64 + lk);
        bf16x8 bs1 = *reinterpret_cast<const bf16x8*>(sb + (sloc + sh * 16 + lr) * 64 + 32 + lk);
#pragma unroll
        for (int gg = 0; gg < 2; ++gg) {
            bf16x8 ag0 = *reinterpret_cast<const bf16x8*>(wta + (gh * 32 + gg * 16 + lr) * 64 + lk);
            bf16x8 ag1 = *reinterpret_cast<const bf16x8*>(wta + (gh * 32 + gg * 16 + lr) * 64 + 32 + lk);
            f32x4 uacc = {};
            uacc = __builtin_amdgcn_mfma_f32_16x16x32_bf16(ag0, bs0, uacc, 0, 0, 0);
            uacc = __builtin_amdgcn_mfma_f32_16x16x32_bf16(ag1, bs1, uacc, 0, 0, 0);
            // lane holds U[s = sh*16+lr][g = gh*32+gg*16+rr+q], q=0..3
            union { unsigned short h[4]; unsigned long long ull; } pk;
#pragma unroll
            for (int q = 0; q < 4; ++q) pk.h[q] = f2bf(uacc[q]);
            *reinterpret_cast<unsigned long long*>(uls + (sh * 16 + lr) * 72 + gh * 32 + gg * 16 + rr) = pk.ull;
        }
    }
    __syncthreads();

    // B-frags: U-local rows rg*16+lr (read once from LDS)
    bf16x8 bU0[2], bU1[2];
#pragma unroll
    for (int rg = 0; rg < 2; ++rg) {
        bU0[rg] = *reinterpret_cast<const bf16x8*>(uls + (rg * 16 + lr) * 72 + lk);
        bU1[rg] = *reinterpret_cast<const bf16x8*>(uls + (rg * 16 + lr) * 72 + 32 + lk);
    }

    // ---- t-sweep: wave w covers t in [w*256, w*256+256) for all 32 rows ----
    int t0w = wid * 256;
    float* ob0 = out + (R0 + lr) * 1024 + rr;        // rows R0..R0+15
    float* ob1 = out + (R0 + 16 + lr) * 1024 + rr;   // rows R0+16..R0+31

#pragma unroll 16
    for (int mm = 0; mm < 16; ++mm) {
        int t0 = t0w + mm * 16;
        bf16x8 a0 = *reinterpret_cast<const bf16x8*>(sb + (t0 + lr) * 64 + lk);
        bf16x8 a1 = *reinterpret_cast<const bf16x8*>(sb + (t0 + lr) * 64 + 32 + lk);
        f32x4 acc0 = {}, acc1 = {};
        acc0 = __builtin_amdgcn_mfma_f32_16x16x32_bf16(a0, bU0[0], acc0, 0, 0, 0);
        acc0 = __builtin_amdgcn_mfma_f32_16x16x32_bf16(a1, bU1[0], acc0, 0, 0, 0);
        acc1 = __builtin_amdgcn_mfma_f32_16x16x32_bf16(a0, bU0[1], acc1, 0, 0, 0);
        acc1 = __builtin_amdgcn_mfma_f32_16x16x32_bf16(a1, bU1[1], acc1, 0, 0, 0);
        // lane: out[R0 + rg*16 + lr][t0 + rr + q] -> one 16B store per chain
        *reinterpret_cast<f32x4*>(ob0 + t0) = acc0;
        *reinterpret_cast<f32x4*>(ob1 + t0) = acc1;
    }
}

extern "C" void kernel_launch(void* const* d_in, const int* in_sizes, int n_in,
                              void* d_out, int out_size, void* d_ws, size_t ws_size,
                              hipStream_t stream) {
    const float* state = (const float*)d_in[0];   // 1024 x 64
    const float* act   = (const float*)d_in[1];   // 64 x 32
    const float* core  = (const float*)d_in[2];   // 32 x 64 x 64
    float* out = (float*)d_out;                   // 64 x 1024 x 1024

    unsigned short* sb = (unsigned short*)d_ws;   // state bf16: 65536 (128 KB)
    unsigned short* wt = sb + 65536;              // Wt bf16:   262144 (512 KB)

    prep<<<256, 256, 0, stream>>>(state, act, core, sb, wt);
    gemm<<<2048, 256, 0, stream>>>(sb, wt, out);
}